// Round 13
// baseline (171.352 us; speedup 1.0000x reference)
//
#include <hip/hip_runtime.h>

#define P 256     // H*W
#define CDIM 256
#define SDIM 32

typedef __attribute__((ext_vector_type(8))) short short8;   // 8 bf16 = 4 VGPR
typedef __attribute__((ext_vector_type(4))) float f32x4;
typedef __attribute__((ext_vector_type(4))) unsigned int uint4v;

__device__ inline unsigned int pack2bf(float lo, float hi) {
    unsigned int ul = __builtin_bit_cast(unsigned int, lo);
    unsigned int uh = __builtin_bit_cast(unsigned int, hi);
    ul += 0x7fffu + ((ul >> 16) & 1u);   // RNE
    uh += 0x7fffu + ((uh >> 16) & 1u);
    return (ul >> 16) | (uh & 0xffff0000u);
}

// Fused prep. Blocks [0,1024): eh (4 a-rows x 256 p). Blocks [1024,1056):
// pack W1e -> bf16 MFMA-A-fragment-linear ([m'=a>>4][kc=k>>3][i16=a&15][8]).
__global__ __launch_bounds__(256) void prep_kernel(const float* __restrict__ hid,
                                                   const float* __restrict__ W1,
                                                   const float* __restrict__ b1,
                                                   float* __restrict__ ehb1,
                                                   uint4v* __restrict__ packA) {
    const int blk = blockIdx.x;
    const int tid = threadIdx.x;
    if (blk >= 1024) {
        const int t  = (blk - 1024) * 256 + tid;   // [0, 8192)
        const int a  = ((t >> 9) << 4) | (t & 15);
        const int kc = (t >> 4) & 31;
        const float* src = W1 + (size_t)a * 512 + 256 + kc * 8;
        const float4 f0 = *(const float4*)src;
        const float4 f1 = *(const float4*)(src + 4);
        uint4v u;
        u.x = pack2bf(f0.x, f0.y);
        u.y = pack2bf(f0.z, f0.w);
        u.z = pack2bf(f1.x, f1.y);
        u.w = pack2bf(f1.z, f1.w);
        packA[t] = u;
        return;
    }
    // eh: ehb1[b,a,p] = sum_c W1h[a,c]*hid[b,c,p] + b1[a]  (fp32, exact)
    const int b  = blk >> 6;
    const int a0 = (blk & 63) << 2;    // 4 a-rows per block (uniform -> s_load W1)
    const int p  = tid;
    float acc[4];
#pragma unroll
    for (int i = 0; i < 4; ++i) acc[i] = 0.f;
    const float* hb = hid + (size_t)b * CDIM * P;
    for (int c = 0; c < CDIM; c += 8) {
        float hv[8];
#pragma unroll
        for (int j = 0; j < 8; ++j) hv[j] = hb[(c + j) * P + p];
#pragma unroll
        for (int i = 0; i < 4; ++i) {
            const float* wr = W1 + (size_t)(a0 + i) * 512 + c;
#pragma unroll
            for (int j = 0; j < 8; ++j) acc[i] = fmaf(wr[j], hv[j], acc[i]);
        }
    }
#pragma unroll
    for (int i = 0; i < 4; ++i)
        ehb1[((size_t)b * CDIM + a0 + i) * P + p] = acc[i] + b1[a0 + i];
}

// Kernel B, templated for phase ablation (V0 = real kernel, identical to r12):
//   V0: DMA + TRANSPOSE + MFMA + epilogue   (writes real partial)
//   V1: DMA + TRANSPOSE + epilogue          (no af/MFMA)
//   V2: DMA + barriers only                 (stream skeleton, token read)
//   V3: TRANSPOSE + MFMA + epilogue         (no DMA, stale LDS)
// Probes write only to the partial region (consumed by context BEFORE probes
// run; re-written by V0 on every call -> deterministic, d_out unaffected).
template <int V>
__global__ __launch_bounds__(256, 4) void energy_mfma(const float* __restrict__ enc,
                                                      const unsigned char* __restrict__ packA,
                                                      const float* __restrict__ W2,
                                                      const float* __restrict__ ehb1,
                                                      float* __restrict__ partial) {
    constexpr bool DO_DMA  = (V != 3);
    constexpr bool DO_TR   = (V != 2);
    constexpr bool DO_MFMA = (V == 0 || V == 3);
    constexpr bool DO_ACC  = (V != 2);

    __shared__ __align__(16) unsigned char bufF[64 * 256];   // fp32 [64c][64p] linear, 16KB
    __shared__ __align__(16) unsigned char ldsB[64 * 128];   // bf16 [64p][64c] swz, 8KB
    __shared__ float red[4];
    const int bid = blockIdx.x;          // 2048
    const int bs  = bid >> 2;            // b*32+s
    const int pq  = bid & 3;             // p-quarter (64p)
    const int b   = bs >> 5;
    const int tid = threadIdx.x;
    const int l   = tid & 63;
    const int w   = tid >> 6;            // wave 0..3 -> a-slice
    const int g   = l >> 4;
    const int i16 = l & 15;
    const int a_base = w * 64;
    const int p_r = tid & 63;            // transpose: pixel
    const int ch  = tid >> 6;            // transpose: 16-c group (== wave)
    const float* eb   = enc  + (size_t)bs * (CDIM * P) + pq * 64;
    const float* ehbB = ehb1 + (size_t)b  * (CDIM * P) + pq * 64;

#define DMA_TILE(KT)                                                               \
    {                                                                              \
        const float* gsrc = eb + (size_t)((KT) * 64 + w * 16) * P;                 \
        unsigned char* ldst = bufF + (w * 16) * 256;                               \
        _Pragma("unroll")                                                          \
        for (int i_ = 0; i_ < 4; ++i_) {                                           \
            __builtin_amdgcn_global_load_lds(                                      \
                (const unsigned int*)(gsrc + (size_t)(i_ * 4 + (l >> 4)) * P +     \
                                      (l & 15) * 4),                               \
                (unsigned int*)(ldst + i_ * 1024), 16, 0, 0);                      \
        }                                                                          \
    }

#define TRANSPOSE()                                                                \
    {                                                                              \
        float cv[16];                                                              \
        _Pragma("unroll")                                                          \
        for (int j_ = 0; j_ < 16; ++j_)                                            \
            cv[j_] = *(const float*)(bufF + (ch * 16 + j_) * 256 + p_r * 4);       \
        unsigned char* dst = ldsB + p_r * 128;                                     \
        _Pragma("unroll")                                                          \
        for (int h_ = 0; h_ < 2; ++h_) {                                           \
            uint4v u;                                                              \
            u.x = pack2bf(cv[h_*8+0], cv[h_*8+1]);                                 \
            u.y = pack2bf(cv[h_*8+2], cv[h_*8+3]);                                 \
            u.z = pack2bf(cv[h_*8+4], cv[h_*8+5]);                                 \
            u.w = pack2bf(cv[h_*8+6], cv[h_*8+7]);                                 \
            *(uint4v*)(dst + ((ch * 32 + h_ * 16) ^ ((p_r & 7) << 4))) = u;        \
        }                                                                          \
    }

    // ---- prologue ----
    if constexpr (DO_DMA) DMA_TILE(0);
    f32x4 acc[4][4];
    if constexpr (DO_ACC) {
#pragma unroll
        for (int m = 0; m < 4; ++m) {
#pragma unroll
            for (int r = 0; r < 4; ++r) {
                const int a = a_base + m * 16 + g * 4 + r;
                const float* ehr = ehbB + (size_t)a * P + i16;
#pragma unroll
                for (int n = 0; n < 4; ++n)
                    acc[m][n][r] = ehr[n * 16];   // C/D layout: row=(lane>>4)*4+reg
            }
        }
    }
    __syncthreads();   // drains vmcnt(0): DMA0 (+acc loads) done

#pragma unroll
    for (int kt = 0; kt < 4; ++kt) {
        if constexpr (DO_TR) TRANSPOSE();
        __syncthreads();                 // ldsB ready; bufF consumed
        if (kt < 3) { if constexpr (DO_DMA) DMA_TILE(kt + 1); }
        if constexpr (DO_MFMA) {
#pragma unroll
            for (int kh = 0; kh < 2; ++kh) {
                short8 af[4], bf[4];
#pragma unroll
                for (int m = 0; m < 4; ++m) {
                    const int chunk = ((a_base >> 4) + m) * 32 + kt * 8 + kh * 4;
                    af[m] = __builtin_bit_cast(short8,
                        *(const uint4v*)(packA + (size_t)chunk * 256 + l * 16));
                }
#pragma unroll
                for (int n = 0; n < 4; ++n) {
                    const int row = n * 16 + i16;
                    bf[n] = __builtin_bit_cast(short8,
                        *(const uint4v*)(ldsB + row * 128 +
                                         (((kh * 4 + g) * 16) ^ ((row & 7) << 4))));
                }
#pragma unroll
                for (int m = 0; m < 4; ++m)
#pragma unroll
                    for (int n = 0; n < 4; ++n)
                        acc[m][n] = __builtin_amdgcn_mfma_f32_16x16x32_bf16(af[m], bf[n], acc[m][n], 0, 0, 0);
            }
        }
        __syncthreads();   // drains vmcnt(0): DMA(kt+1) done; ldsB consumed
    }
#undef DMA_TILE
#undef TRANSPOSE

    if constexpr (DO_ACC) {
        // epilogue: W2 (L2) + pure-VALU tanh/dot, 4 independent m-chains
        float epm[4];
#pragma unroll
        for (int m = 0; m < 4; ++m) {
            float e = 0.f;
#pragma unroll
            for (int r = 0; r < 4; ++r) {
                const float wv = W2[a_base + m * 16 + g * 4 + r];
#pragma unroll
                for (int n = 0; n < 4; ++n) {
                    const float x  = acc[m][n][r];
                    const float ex = __expf(2.f * x);
                    const float t  = 1.f - 2.f / (ex + 1.f);
                    e = fmaf(wv, t, e);
                }
            }
            epm[m] = e;
        }
        float ep = (epm[0] + epm[1]) + (epm[2] + epm[3]);
#pragma unroll
        for (int off = 32; off > 0; off >>= 1) ep += __shfl_down(ep, off, 64);
        if (l == 0) red[w] = ep;
        __syncthreads();
        if (tid == 0)
            partial[(size_t)bs * 4 + pq] = red[0] + red[1] + red[2] + red[3];
    } else {
        // V2: token LDS read, kept alive (rule #17) so DMA isn't DCE-able
        float t0 = *(const float*)(bufF + tid * 16);
        asm volatile("" :: "v"(t0));
        if (tid == 0) partial[bid] = t0;
    }
}

// Kernel D: fused softmax + context.
__global__ __launch_bounds__(256) void context_kernel(const float4* __restrict__ enc4,
                                                      const float* __restrict__ partial,
                                                      const float* __restrict__ b2,
                                                      float4* __restrict__ out4) {
    const int bi = blockIdx.x;                       // 1024
    const int b  = bi >> 6;
    const int i4 = ((bi & 63) << 8) + threadIdx.x;   // [0,16384) float4s over C*P

    float e[SDIM];
    const float* pb = partial + (size_t)b * SDIM * 4;
    const float bias = b2[0];
#pragma unroll
    for (int s = 0; s < SDIM; ++s)
        e[s] = (pb[s*4] + pb[s*4+1] + pb[s*4+2] + pb[s*4+3]) * (1.f / 256.f) + bias;
    float m = e[0];
#pragma unroll
    for (int s = 1; s < SDIM; ++s) m = fmaxf(m, e[s]);
    float sum = 0.f;
#pragma unroll
    for (int s = 0; s < SDIM; ++s) { e[s] = __expf(e[s] - m); sum += e[s]; }
    const float inv = 1.f / sum;

    float4 acc = {0.f, 0.f, 0.f, 0.f};
    const float4* eb = enc4 + (size_t)b * SDIM * 16384 + i4;
#pragma unroll 4
    for (int s = 0; s < SDIM; ++s) {
        const float wv = e[s] * inv;
        const float4 v = eb[(size_t)s * 16384];
        acc.x = fmaf(wv, v.x, acc.x);
        acc.y = fmaf(wv, v.y, acc.y);
        acc.z = fmaf(wv, v.z, acc.z);
        acc.w = fmaf(wv, v.w, acc.w);
    }
    out4[(size_t)b * 16384 + i4] = acc;
}

extern "C" void kernel_launch(void* const* d_in, const int* in_sizes, int n_in,
                              void* d_out, int out_size, void* d_ws, size_t ws_size,
                              hipStream_t stream) {
    const float* hid = (const float*)d_in[0];
    const float* enc = (const float*)d_in[1];
    const float* W1  = (const float*)d_in[2];
    const float* b1  = (const float*)d_in[3];
    const float* W2  = (const float*)d_in[4];
    const float* b2  = (const float*)d_in[5];
    float* out = (float*)d_out;

    float* ehb1    = out;                       // d_out reused as 4MB scratch
    float* partial = (float*)d_ws;              // 2048 floats
    unsigned char* packA = (unsigned char*)(partial + 2048);  // 128KB bf16 W1e

    prep_kernel<<<1056, 256, 0, stream>>>(hid, W1, b1, ehb1, (uint4v*)packA);
    energy_mfma<0><<<2048, 256, 0, stream>>>(enc, packA, W2, ehb1, partial);
    context_kernel<<<1024, 256, 0, stream>>>((const float4*)enc, partial, b2, (float4*)out);
    // ---- ablation probes (diagnostic only; write to consumed partial scratch) ----
    energy_mfma<1><<<2048, 256, 0, stream>>>(enc, packA, W2, ehb1, partial);
    energy_mfma<2><<<2048, 256, 0, stream>>>(enc, packA, W2, ehb1, partial);
    energy_mfma<3><<<2048, 256, 0, stream>>>(enc, packA, W2, ehb1, partial);
}

// Round 14
// 91.658 us; speedup vs baseline: 1.8695x; 1.8695x over previous
//
#include <hip/hip_runtime.h>

#define P 256     // H*W
#define CDIM 256
#define SDIM 32

typedef __attribute__((ext_vector_type(8))) short short8;   // 8 bf16 = 4 VGPR
typedef __attribute__((ext_vector_type(4))) float f32x4;
typedef __attribute__((ext_vector_type(4))) unsigned int uint4v;

__device__ inline unsigned int pack2bf(float lo, float hi) {
    unsigned int ul = __builtin_bit_cast(unsigned int, lo);
    unsigned int uh = __builtin_bit_cast(unsigned int, hi);
    ul += 0x7fffu + ((ul >> 16) & 1u);   // RNE
    uh += 0x7fffu + ((uh >> 16) & 1u);
    return (ul >> 16) | (uh & 0xffff0000u);
}

// Fused prep. Blocks [0,1024): eh (4 a-rows x 256 p). Blocks [1024,1056):
// pack W1e -> bf16 MFMA-A-fragment-linear ([m'=a>>4][kc=k>>3][i16=a&15][8]).
__global__ __launch_bounds__(256) void prep_kernel(const float* __restrict__ hid,
                                                   const float* __restrict__ W1,
                                                   const float* __restrict__ b1,
                                                   float* __restrict__ ehb1,
                                                   uint4v* __restrict__ packA) {
    const int blk = blockIdx.x;
    const int tid = threadIdx.x;
    if (blk >= 1024) {
        const int t  = (blk - 1024) * 256 + tid;   // [0, 8192)
        const int a  = ((t >> 9) << 4) | (t & 15);
        const int kc = (t >> 4) & 31;
        const float* src = W1 + (size_t)a * 512 + 256 + kc * 8;
        const float4 f0 = *(const float4*)src;
        const float4 f1 = *(const float4*)(src + 4);
        uint4v u;
        u.x = pack2bf(f0.x, f0.y);
        u.y = pack2bf(f0.z, f0.w);
        u.z = pack2bf(f1.x, f1.y);
        u.w = pack2bf(f1.z, f1.w);
        packA[t] = u;
        return;
    }
    // eh: ehb1[b,a,p] = sum_c W1h[a,c]*hid[b,c,p] + b1[a]  (fp32, exact)
    const int b  = blk >> 6;
    const int a0 = (blk & 63) << 2;    // 4 a-rows per block (uniform -> s_load W1)
    const int p  = tid;
    float acc[4];
#pragma unroll
    for (int i = 0; i < 4; ++i) acc[i] = 0.f;
    const float* hb = hid + (size_t)b * CDIM * P;
    for (int c = 0; c < CDIM; c += 8) {
        float hv[8];
#pragma unroll
        for (int j = 0; j < 8; ++j) hv[j] = hb[(c + j) * P + p];
#pragma unroll
        for (int i = 0; i < 4; ++i) {
            const float* wr = W1 + (size_t)(a0 + i) * 512 + c;
#pragma unroll
            for (int j = 0; j < 8; ++j) acc[i] = fmaf(wr[j], hv[j], acc[i]);
        }
    }
#pragma unroll
    for (int i = 0; i < 4; ++i)
        ehb1[((size_t)b * CDIM + a0 + i) * P + p] = acc[i] + b1[a0 + i];
}

// Kernel B: bf16-MFMA energy — REGISTER-FED version.
// r13 ablation: DMA/transpose/epilogue/barriers ~ free; 75 of 77 µs sat in the
// af+MFMA phase. Cause: __launch_bounds__(256,4) -> 128-reg budget -> 64-VGPR
// allocation -> af/bf loads serialized at L2 latency. Fix: (256,1) register
// freedom + af double-buffered one kt ahead (8 loads land under the ~600-cyc
// MFMA phase). No asm waits, no sched pins — compiler schedules.
__global__ __launch_bounds__(256, 1) void energy_mfma(const float* __restrict__ enc,
                                                      const unsigned char* __restrict__ packA,
                                                      const float* __restrict__ W2,
                                                      const float* __restrict__ ehb1,
                                                      float* __restrict__ partial) {
    __shared__ __align__(16) unsigned char bufF[64 * 256];   // fp32 [64c][64p] linear, 16KB
    __shared__ __align__(16) unsigned char ldsB[64 * 128];   // bf16 [64p][64c] swz, 8KB
    __shared__ float red[4];
    const int bid = blockIdx.x;          // 2048
    const int bs  = bid >> 2;            // b*32+s
    const int pq  = bid & 3;             // p-quarter (64p)
    const int b   = bs >> 5;
    const int tid = threadIdx.x;
    const int l   = tid & 63;
    const int w   = tid >> 6;            // wave 0..3 -> a-slice
    const int g   = l >> 4;
    const int i16 = l & 15;
    const int a_base = w * 64;
    const int p_r = tid & 63;            // transpose: pixel
    const int ch  = tid >> 6;            // transpose: 16-c group (== wave)
    const float* eb   = enc  + (size_t)bs * (CDIM * P) + pq * 64;
    const float* ehbB = ehb1 + (size_t)b  * (CDIM * P) + pq * 64;

#define DMA_TILE(KT)                                                               \
    {                                                                              \
        const float* gsrc = eb + (size_t)((KT) * 64 + w * 16) * P;                 \
        unsigned char* ldst = bufF + (w * 16) * 256;                               \
        _Pragma("unroll")                                                          \
        for (int i_ = 0; i_ < 4; ++i_) {                                           \
            __builtin_amdgcn_global_load_lds(                                      \
                (const unsigned int*)(gsrc + (size_t)(i_ * 4 + (l >> 4)) * P +     \
                                      (l & 15) * 4),                               \
                (unsigned int*)(ldst + i_ * 1024), 16, 0, 0);                      \
        }                                                                          \
    }

#define TRANSPOSE()                                                                \
    {                                                                              \
        float cv[16];                                                              \
        _Pragma("unroll")                                                          \
        for (int j_ = 0; j_ < 16; ++j_)                                            \
            cv[j_] = *(const float*)(bufF + (ch * 16 + j_) * 256 + p_r * 4);       \
        unsigned char* dst = ldsB + p_r * 128;                                     \
        _Pragma("unroll")                                                          \
        for (int h_ = 0; h_ < 2; ++h_) {                                           \
            uint4v u;                                                              \
            u.x = pack2bf(cv[h_*8+0], cv[h_*8+1]);                                 \
            u.y = pack2bf(cv[h_*8+2], cv[h_*8+3]);                                 \
            u.z = pack2bf(cv[h_*8+4], cv[h_*8+5]);                                 \
            u.w = pack2bf(cv[h_*8+6], cv[h_*8+7]);                                 \
            *(uint4v*)(dst + ((ch * 32 + h_ * 16) ^ ((p_r & 7) << 4))) = u;        \
        }                                                                          \
    }

    // af loads for one kt: 8 independent dwordx4 from packA (L2), lane-linear.
#define LOAD_AF(DST, KT)                                                           \
    {                                                                              \
        _Pragma("unroll")                                                          \
        for (int kh_ = 0; kh_ < 2; ++kh_)                                          \
            _Pragma("unroll")                                                      \
            for (int m_ = 0; m_ < 4; ++m_) {                                       \
                const int chunk = ((a_base >> 4) + m_) * 32 + (KT) * 8 + kh_ * 4;  \
                DST[kh_][m_] = __builtin_bit_cast(short8,                          \
                    *(const uint4v*)(packA + (size_t)chunk * 256 + l * 16));       \
            }                                                                      \
    }

    // ---- prologue: DMA tile 0; acc-init + af(kt=0) ride under it ----
    DMA_TILE(0);
    f32x4 acc[4][4];
#pragma unroll
    for (int m = 0; m < 4; ++m) {
#pragma unroll
        for (int r = 0; r < 4; ++r) {
            const int a = a_base + m * 16 + g * 4 + r;
            const float* ehr = ehbB + (size_t)a * P + i16;
#pragma unroll
            for (int n = 0; n < 4; ++n)
                acc[m][n][r] = ehr[n * 16];   // C/D layout: row=(lane>>4)*4+reg
        }
    }
    short8 afA[2][4], afB[2][4];
    LOAD_AF(afA, 0);
    __syncthreads();   // drains vmcnt(0): DMA0 + acc + af0 done; bufF ready

#pragma unroll
    for (int kt = 0; kt < 4; ++kt) {
        TRANSPOSE();
        __syncthreads();                 // ldsB ready; bufF consumed
        if (kt < 3) DMA_TILE(kt + 1);    // HBM, hides under MFMA below
        if (kt == 0) LOAD_AF(afB, 1);    // L2, hides under MFMA below
        if (kt == 1) LOAD_AF(afA, 2);
        if (kt == 2) LOAD_AF(afB, 3);
#pragma unroll
        for (int kh = 0; kh < 2; ++kh) {
            short8 bf[4];
#pragma unroll
            for (int n = 0; n < 4; ++n) {
                const int row = n * 16 + i16;
                bf[n] = __builtin_bit_cast(short8,
                    *(const uint4v*)(ldsB + row * 128 +
                                     (((kh * 4 + g) * 16) ^ ((row & 7) << 4))));
            }
            if ((kt & 1) == 0) {
#pragma unroll
                for (int m = 0; m < 4; ++m)
#pragma unroll
                    for (int n = 0; n < 4; ++n)
                        acc[m][n] = __builtin_amdgcn_mfma_f32_16x16x32_bf16(afA[kh][m], bf[n], acc[m][n], 0, 0, 0);
            } else {
#pragma unroll
                for (int m = 0; m < 4; ++m)
#pragma unroll
                    for (int n = 0; n < 4; ++n)
                        acc[m][n] = __builtin_amdgcn_mfma_f32_16x16x32_bf16(afB[kh][m], bf[n], acc[m][n], 0, 0, 0);
            }
        }
        __syncthreads();   // DMA(kt+1)+af(kt+1) done; ldsB consumed
    }
#undef DMA_TILE
#undef TRANSPOSE
#undef LOAD_AF

    // epilogue: W2 (L2) + pure-VALU tanh/dot, 4 independent m-chains
    float epm[4];
#pragma unroll
    for (int m = 0; m < 4; ++m) {
        float e = 0.f;
#pragma unroll
        for (int r = 0; r < 4; ++r) {
            const float wv = W2[a_base + m * 16 + g * 4 + r];
#pragma unroll
            for (int n = 0; n < 4; ++n) {
                const float x  = acc[m][n][r];
                const float ex = __expf(2.f * x);
                const float t  = 1.f - 2.f / (ex + 1.f);
                e = fmaf(wv, t, e);
            }
        }
        epm[m] = e;
    }
    float ep = (epm[0] + epm[1]) + (epm[2] + epm[3]);
#pragma unroll
    for (int off = 32; off > 0; off >>= 1) ep += __shfl_down(ep, off, 64);
    if (l == 0) red[w] = ep;
    __syncthreads();
    if (tid == 0)
        partial[(size_t)bs * 4 + pq] = red[0] + red[1] + red[2] + red[3];
}

// Kernel D: fused softmax + context.
__global__ __launch_bounds__(256) void context_kernel(const float4* __restrict__ enc4,
                                                      const float* __restrict__ partial,
                                                      const float* __restrict__ b2,
                                                      float4* __restrict__ out4) {
    const int bi = blockIdx.x;                       // 1024
    const int b  = bi >> 6;
    const int i4 = ((bi & 63) << 8) + threadIdx.x;   // [0,16384) float4s over C*P

    float e[SDIM];
    const float* pb = partial + (size_t)b * SDIM * 4;
    const float bias = b2[0];
#pragma unroll
    for (int s = 0; s < SDIM; ++s)
        e[s] = (pb[s*4] + pb[s*4+1] + pb[s*4+2] + pb[s*4+3]) * (1.f / 256.f) + bias;
    float m = e[0];
#pragma unroll
    for (int s = 1; s < SDIM; ++s) m = fmaxf(m, e[s]);
    float sum = 0.f;
#pragma unroll
    for (int s = 0; s < SDIM; ++s) { e[s] = __expf(e[s] - m); sum += e[s]; }
    const float inv = 1.f / sum;

    float4 acc = {0.f, 0.f, 0.f, 0.f};
    const float4* eb = enc4 + (size_t)b * SDIM * 16384 + i4;
#pragma unroll 4
    for (int s = 0; s < SDIM; ++s) {
        const float wv = e[s] * inv;
        const float4 v = eb[(size_t)s * 16384];
        acc.x = fmaf(wv, v.x, acc.x);
        acc.y = fmaf(wv, v.y, acc.y);
        acc.z = fmaf(wv, v.z, acc.z);
        acc.w = fmaf(wv, v.w, acc.w);
    }
    out4[(size_t)b * 16384 + i4] = acc;
}

extern "C" void kernel_launch(void* const* d_in, const int* in_sizes, int n_in,
                              void* d_out, int out_size, void* d_ws, size_t ws_size,
                              hipStream_t stream) {
    const float* hid = (const float*)d_in[0];
    const float* enc = (const float*)d_in[1];
    const float* W1  = (const float*)d_in[2];
    const float* b1  = (const float*)d_in[3];
    const float* W2  = (const float*)d_in[4];
    const float* b2  = (const float*)d_in[5];
    float* out = (float*)d_out;

    float* ehb1    = out;                       // d_out reused as 4MB scratch
    float* partial = (float*)d_ws;              // 2048 floats
    unsigned char* packA = (unsigned char*)(partial + 2048);  // 128KB bf16 W1e

    prep_kernel<<<1056, 256, 0, stream>>>(hid, W1, b1, ehb1, (uint4v*)packA);
    energy_mfma<<<2048, 256, 0, stream>>>(enc, packA, W2, ehb1, partial);
    context_kernel<<<1024, 256, 0, stream>>>((const float4*)enc, partial, b2, (float4*)out);
}